// Round 1
// baseline (130.114 us; speedup 1.0000x reference)
//
#include <hip/hip_runtime.h>
#include <math.h>
#include <float.h>

// LearnedRouter: B=4, S=4096, D=1024, N=256, TOPK=8
// Outputs (concat, fp32): token_repr[B,S,D], bank_indices[B,S], weights[B,S,N], topk_idx[B,S,8]

namespace {
constexpr int kB = 4, kS = 4096, kD = 1024, kN = 256, kK = 8;
constexpr float kScale = 0.03125f;   // 1/sqrt(1024)
constexpr float kNeg = -1e9f;
constexpr size_t kBankOff = (size_t)kB * kS * kD;            // 16777216
constexpr size_t kWOff    = kBankOff + (size_t)kB * kS;      // 16793600
constexpr size_t kTopkOff = kWOff + (size_t)kB * kS * kN;    // 20987904
}

// ---------------------------------------------------------------------------
// Kernel 1: R[n,d] = kScale * sum_e dr[n,e] * Wq[e,d]
//           bias[n] = kScale * sum_e bq[e] * dr[n,e]
// Grid (32,32) blocks of 256 threads; block tile = 8 n x 32 d, full K=1024.
// Wq/dr stream through L1/L2 (Wq is 4MiB, dr 1MiB; heavy L2 reuse across blocks).
// ---------------------------------------------------------------------------
__global__ __launch_bounds__(256) void k_prep(const float* __restrict__ dr,
                                              const float* __restrict__ wq,
                                              const float* __restrict__ bq,
                                              float* __restrict__ R,
                                              float* __restrict__ bias) {
  const int t = threadIdx.x;
  const int n = blockIdx.x * 8 + (t >> 5);
  const int d = blockIdx.y * 32 + (t & 31);
  const float4* dr4 = reinterpret_cast<const float4*>(dr + (size_t)n * kD);
  float acc = 0.f;
#pragma unroll 4
  for (int e4 = 0; e4 < kD / 4; ++e4) {
    const float4 a = dr4[e4];
    const float* w = wq + (size_t)(e4 * 4) * kD + d;
    acc += a.x * w[0];
    acc += a.y * w[kD];
    acc += a.z * w[2 * kD];
    acc += a.w * w[3 * kD];
  }
  R[(size_t)n * kD + d] = acc * kScale;

  if (blockIdx.y == 0) {
    const int l = t & 31;
    const float* drow = dr + (size_t)n * kD;
    float p = 0.f;
#pragma unroll 4
    for (int i = 0; i < 32; ++i) p += bq[l * 32 + i] * drow[l * 32 + i];
#pragma unroll
    for (int off = 16; off; off >>= 1) p += __shfl_down(p, off, 32);
    if (l == 0) bias[n] = p * kScale;
  }
}

// ---------------------------------------------------------------------------
// Kernel 2: one wave (64 lanes) per token. 4096 blocks x 256 threads.
// Per token: gather 8 set ids, 8 fp32 dots ts.R[n] (wave-parallel, shfl_xor
// reduce), per-lane-redundant dedup + top-k sort + softmax (all static reg
// indexing), then coalesced writes of weights row, token_repr, topk, bank.
// ---------------------------------------------------------------------------
__global__ __launch_bounds__(256) void k_main(const float* __restrict__ ts,
                                              const float* __restrict__ ss,
                                              const int* __restrict__ t2s,
                                              const float* __restrict__ R,
                                              const float* __restrict__ bias,
                                              const float* __restrict__ temp_p,
                                              float* __restrict__ out) {
  const int lane = threadIdx.x & 63;
  const int wid = threadIdx.x >> 6;
  const int bid = blockIdx.x;
  // XCD-aware swizzle: XCD pair (2b,2b+1) owns batch b -> its set_states/R
  // stay L2-resident (2 MiB working set vs 4 MiB L2/XCD).
  const int xcd = bid & 7;
  const int b = xcd >> 1;
  const int s = ((bid >> 3) << 2) + wid + ((xcd & 1) << 11);
  const size_t row = (size_t)b * kS + s;

  // token row: 16 floats/lane in registers
  const float4* ts4 = reinterpret_cast<const float4*>(ts) + row * (kD / 4);
  const float4 tv0 = ts4[lane];
  const float4 tv1 = ts4[64 + lane];
  const float4 tv2 = ts4[128 + lane];
  const float4 tv3 = ts4[192 + lane];

  int nraw[kK], nk[kK];
  float sc[kK];
#pragma unroll
  for (int k = 0; k < kK; ++k) nraw[k] = t2s[s * kK + k];

#pragma unroll
  for (int k = 0; k < kK; ++k) {
    int n = nraw[k];
    n = n < 0 ? 0 : (n > kN - 1 ? kN - 1 : n);
    nk[k] = n;
    const float4* r4 = reinterpret_cast<const float4*>(R) + (size_t)n * (kD / 4);
    const float4 r0 = r4[lane];
    const float4 r1 = r4[64 + lane];
    const float4 r2 = r4[128 + lane];
    const float4 r3 = r4[192 + lane];
    float a = tv0.x * r0.x + tv0.y * r0.y + tv0.z * r0.z + tv0.w * r0.w;
    a += tv1.x * r1.x + tv1.y * r1.y + tv1.z * r1.z + tv1.w * r1.w;
    a += tv2.x * r2.x + tv2.y * r2.y + tv2.z * r2.z + tv2.w * r2.w;
    a += tv3.x * r3.x + tv3.y * r3.y + tv3.z * r3.z + tv3.w * r3.w;
#pragma unroll
    for (int off = 32; off; off >>= 1) a += __shfl_xor(a, off);
    sc[k] = a + bias[n];
  }

  // validity + dedup (mask semantics of reference scatter-max)
  int validmask = 0;
#pragma unroll
  for (int k = 0; k < kK; ++k) {
    bool v = (nraw[k] >= 0);
#pragma unroll
    for (int j = 0; j < kK; ++j)
      if (j < k && nk[j] == nk[k]) v = false;
    if (v) validmask |= (1 << k);
  }
  const int cnt = __popc(validmask);

  // selection sort into 8 slots: key = (score desc, index asc); invalid -> -FLT_MAX
  float ssc[kK];
  int sidx[kK];
  int rem = 0xFF;
#pragma unroll
  for (int i = 0; i < kK; ++i) {
    float bs = -INFINITY;
    int bn = 0x7fffffff;
    int bk = 0;
#pragma unroll
    for (int k = 0; k < kK; ++k) {
      const bool avail = (rem >> k) & 1;
      const float v = ((validmask >> k) & 1) ? sc[k] : -FLT_MAX;
      if (avail && (v > bs || (v == bs && nk[k] < bn))) { bs = v; bn = nk[k]; bk = k; }
    }
    rem &= ~(1 << bk);
    ssc[i] = bs;
    sidx[i] = bn;
  }

  // filler slots (jax.lax.top_k tie-break on the NEG plateau: lowest unmasked
  // indices ascending)
  int fill = 0;
#pragma unroll
  for (int i = 0; i < kK; ++i) {
    if (i >= cnt) {
      bool moved = true;
      while (moved) {
        moved = false;
#pragma unroll
        for (int j = 0; j < kK; ++j)
          if (j < cnt && sidx[j] == fill) { ++fill; moved = true; }
      }
      sidx[i] = fill;
      ssc[i] = kNeg;
      ++fill;
    }
  }

  // softmax over kept entries; all non-kept positions underflow to exact 0
  const float temp = fmaxf(temp_p[0], 0.5f);
  const float m = ssc[0];
  float w[kK];
  float denom = 0.f;
#pragma unroll
  for (int i = 0; i < kK; ++i) {
    const float e = (i < cnt) ? expf((ssc[i] - m) / temp) : 0.f;
    w[i] = e;
    denom += e;
  }
#pragma unroll
  for (int i = 0; i < kK; ++i) w[i] /= denom;

  // weights row [N]: float4 per lane, coalesced 1KB/wave
  {
    const int c0 = lane * 4;
    float4 wv = make_float4(0.f, 0.f, 0.f, 0.f);
#pragma unroll
    for (int k = 0; k < kK; ++k) {
      wv.x = (sidx[k] == c0    ) ? w[k] : wv.x;
      wv.y = (sidx[k] == c0 + 1) ? w[k] : wv.y;
      wv.z = (sidx[k] == c0 + 2) ? w[k] : wv.z;
      wv.w = (sidx[k] == c0 + 3) ? w[k] : wv.w;
    }
    reinterpret_cast<float4*>(out + kWOff)[row * (kN / 4) + lane] = wv;
  }

  // token_repr: sparse weighted sum of <=8 set_states rows
  {
    float4 a0 = make_float4(0.f, 0.f, 0.f, 0.f);
    float4 a1 = a0, a2 = a0, a3 = a0;
#pragma unroll
    for (int k = 0; k < kK; ++k) {
      if (k < cnt) {
        const float wk = w[k];
        const float4* v4 =
            reinterpret_cast<const float4*>(ss) + ((size_t)b * kN + sidx[k]) * (kD / 4);
        float4 v;
        v = v4[lane];        a0.x += wk * v.x; a0.y += wk * v.y; a0.z += wk * v.z; a0.w += wk * v.w;
        v = v4[64 + lane];   a1.x += wk * v.x; a1.y += wk * v.y; a1.z += wk * v.z; a1.w += wk * v.w;
        v = v4[128 + lane];  a2.x += wk * v.x; a2.y += wk * v.y; a2.z += wk * v.z; a2.w += wk * v.w;
        v = v4[192 + lane];  a3.x += wk * v.x; a3.y += wk * v.y; a3.z += wk * v.z; a3.w += wk * v.w;
      }
    }
    float4* o4 = reinterpret_cast<float4*>(out) + row * (kD / 4);
    o4[lane] = a0;
    o4[64 + lane] = a1;
    o4[128 + lane] = a2;
    o4[192 + lane] = a3;
  }

  // topk_idx (as float) + bank_indices (argmax of weights, first-max tie-break)
  if (lane == 0) {
#pragma unroll
    for (int k = 0; k < kK; ++k) out[kTopkOff + row * kK + k] = (float)sidx[k];
    float wm = w[0];
    int bi = sidx[0];
#pragma unroll
    for (int i = 1; i < kK; ++i) {
      if (i < cnt) {
        if (w[i] > wm || (w[i] == wm && sidx[i] < bi)) { wm = w[i]; bi = sidx[i]; }
      }
    }
    out[kBankOff + row] = (float)bi;
  }
}

extern "C" void kernel_launch(void* const* d_in, const int* in_sizes, int n_in,
                              void* d_out, int out_size, void* d_ws, size_t ws_size,
                              hipStream_t stream) {
  const float* ts  = (const float*)d_in[0];   // token_states [4,4096,1024]
  const float* ss  = (const float*)d_in[1];   // set_states   [4,256,1024]
  const float* dr  = (const float*)d_in[2];   // desc_router  [256,1024]
  const int*   t2s = (const int*)  d_in[3];   // token_to_sets[4096,8]
  const float* wq  = (const float*)d_in[4];   // Wq [1024,1024]
  const float* bq  = (const float*)d_in[5];   // bq [1024]
  const float* tmp = (const float*)d_in[6];   // temperature [1]
  float* out = (float*)d_out;

  float* R    = (float*)d_ws;                 // 256*1024 f32 = 1 MiB
  float* bias = R + (size_t)kN * kD;          // 256 f32

  dim3 g1(kN / 8, kD / 32);                   // 32 x 32 = 1024 blocks
  k_prep<<<g1, 256, 0, stream>>>(dr, wq, bq, R, bias);
  k_main<<<kB * kS / 4, 256, 0, stream>>>(ts, ss, t2s, R, bias, tmp, out);
}